// Round 11
// baseline (2333.070 us; speedup 1.0000x reference)
//
#include <hip/hip_runtime.h>

// Sizes (fixed by the problem)
#define DZc 512
#define Bc  64
#define Tc  1000
#define DUc 16
#define DXc 256
#define AROW 552           // padded activation row length (bf16 elems)

// Workspace layout:
//   Wp   : bf16 augmented W' [544 k][512 n] B-fragment order  278528 ushort
//   Bp   : bf16 B_obs in B-fragment order                     131072 ushort
//   zs   : bf16 z-history [T][B][DZ]                          32768000 ushort
//   cnts : per-(group,half) publish counters, 64-B strided    128 u32

typedef __attribute__((ext_vector_type(4))) float f32x4;
typedef __attribute__((ext_vector_type(8))) short s16x8;
typedef __attribute__((ext_vector_type(4))) unsigned u32x4;

__device__ __forceinline__ unsigned short f2bf(float x) {
  unsigned u = __builtin_bit_cast(unsigned, x);
  u = u + 0x7FFFu + ((u >> 16) & 1u);   // round-to-nearest-even
  return (unsigned short)(u >> 16);
}
__device__ __forceinline__ float bf2f(unsigned short u) {
  unsigned x = ((unsigned)u) << 16;
  return __builtin_bit_cast(float, x);
}
// HW packed f32x2 -> bf16x2 convert (no builtin on gfx950; RNE)
__device__ __forceinline__ unsigned cvt_pk_bf16(float lo, float hi) {
  unsigned r;
  asm("v_cvt_pk_bf16_f32 %0, %1, %2" : "=v"(r) : "v"(lo), "v"(hi));
  return r;
}
// even<->odd lane f32 swap (quad_perm [1,0,3,2])
__device__ __forceinline__ float dpp_swap1(float x) {
  int r = __builtin_amdgcn_mov_dpp(__builtin_bit_cast(int, x), 0xB1, 0xF, 0xF, true);
  return __builtin_bit_cast(float, r);
}

// Pack augmented W' into bf16 MFMA B-fragments.
// W'[n][k]: k<512 -> W[n][k]; k in [512,544) -> Wu[n][k&15].
// Fragment (kt,nt): lane l elem j holds B[k][n], n = nt*16+(l&15),
// k = kt*32+(l>>4)*8+j.  Linear: Wp[((kt*32+nt)*64+l)*8+j]
__global__ void pack_w_kernel(const float* __restrict__ W,
                              const float* __restrict__ Wu,
                              unsigned short* __restrict__ Wp) {
  int d = blockIdx.x * 256 + threadIdx.x;          // 278528 total
  int j = d & 7, l = (d >> 3) & 63, nt = (d >> 9) & 31, kt = d >> 14;
  int n = nt * 16 + (l & 15);
  int k = kt * 32 + ((l >> 4) << 3) + j;
  float val = (k < DZc) ? W[n * DZc + k] : Wu[n * DUc + (k & 15)];
  Wp[d] = f2bf(val);
}

// Pack B_obs[512][256] ([z][x]) into bf16 B-fragments: B[k][n] = B_obs[k][n].
__global__ void pack_b_kernel(const float* __restrict__ B,
                              unsigned short* __restrict__ Bp) {
  int d = blockIdx.x * 256 + threadIdx.x;          // 131072 total
  int j = d & 7, l = (d >> 3) & 63, nt = (d >> 9) & 15, kt = d >> 13;
  int n = nt * 16 + (l & 15);
  int k = kt * 32 + ((l >> 4) << 3) + j;
  Bp[d] = f2bf(B[k * DXc + n]);
}

// Recurrence, N-split pairs: 8 active WGs = 4 trial-groups x 2 n-halves.
// 8 waves x 64 (2/SIMD), 16 trials, 256 outputs/CU; 34 W-frags/wave in regs.
// SINGLE barrier per step: {spin -> partner-z load -> insert} pre-barrier,
// all 17 kt MFMAs in one dense post-barrier block, tail {z stores, a writes,
// per-wave vmcnt drain + atomic publish} with no end barrier (double-buffered
// abuf; barrier-interval skew audit: disjoint buffers / disjoint n-ranges).
__global__ __launch_bounds__(512, 2) void rnn_rec_kernel(
    const float* __restrict__ z0, const float* __restrict__ v,
    const float* __restrict__ h, const float* __restrict__ dp,
    const unsigned short* __restrict__ Wp, unsigned short* __restrict__ zs,
    unsigned int* __restrict__ cnts) {
  __shared__ __align__(16) unsigned short abuf[2][16][AROW];   // 34.5 KiB

  const int bid = blockIdx.x;
  const int g = bid & 7;                           // trial group candidate
  const int s = bid >> 3;                          // n-half
  if (g >= 4) return;                              // 8 idle blocks exit
  const int tid = threadIdx.x;
  const int lane = tid & 63;
  const int w = tid >> 6;                          // wave 0..7
  const int l15 = lane & 15;
  const int lg = lane >> 4;
  const int b0 = g * 16;
  const int nbase = s * 256 + w * 32;              // wave's first output

  // ---- one-time: 34 W fragments into regs, straight kt ordering ----
  // c = kt*2 + ntl ; kt 0..15 = W k-tiles of full k, 16 = v tile
  s16x8 wr[34];
#pragma unroll
  for (int kt = 0; kt < 17; ++kt) {
#pragma unroll
    for (int ntl = 0; ntl < 2; ++ntl) {
      int nt = s * 16 + w * 2 + ntl;
      wr[kt * 2 + ntl] =
          *(const s16x8*)(Wp + ((size_t)((kt * 32 + nt) * 64 + lane)) * 8);
    }
  }

  // ---- one-time: z0 into acc, h into regs ----
  float hreg[2];
  f32x4 acc[2];
#pragma unroll
  for (int ntl = 0; ntl < 2; ++ntl) {
    hreg[ntl] = h[nbase + ntl * 16 + l15];
#pragma unroll
    for (int r = 0; r < 4; ++r)
      acc[ntl][r] = z0[(size_t)(b0 + lg * 4 + r) * DZc + nbase + ntl * 16 + l15];
  }
  const float decay = expf(-expf(dp[0]));

  // partner-insert slot: thread -> (trial, 8-k chunk of partner half)
  const int ptrial = tid >> 5;                     // 0..15
  const int koff = (tid & 31) * 8;                 // 0..248
  const int pk = (1 - s) * 256 + koff;             // partner k base
  float hpart[8];
#pragma unroll
  for (int j = 0; j < 8; ++j) hpart[j] = h[pk + j];

  // v staging: threads 0..255 own one (trial, du) slot
  const int du = tid & 15, trr = tid >> 4;
  const size_t vbase = ((size_t)(b0 + trr) * DUc + du) * Tc;
  float vcur = (tid < 256) ? v[vbase] : 0.f;

  // ---- prologue: build FULL a(0) from z0 (f32) + v(0) ----
#pragma unroll
  for (int half = 0; half < 2; ++half) {
    int kk = half * 256 + koff;
    const float* zp = z0 + (size_t)(b0 + ptrial) * DZc + kk;
    s16x8 ov;
#pragma unroll
    for (int j = 0; j < 8; ++j) {
      float av = zp[j] - h[kk + j];
      ov[j] = (short)f2bf(av > 0.f ? av : 0.f);
    }
    *(s16x8*)&abuf[0][ptrial][kk] = ov;
  }
  if (tid < 256) {
    unsigned short hi = f2bf(vcur);
    abuf[0][trr][512 + du] = hi;
    abuf[0][trr][528 + du] = f2bf(vcur - bf2f(hi));
  }

  // publish counters, 64-B strided; consumer waits partner cnt >= 8*t
  unsigned int* mycnt = cnts + (g * 2 + s) * 16;
  const unsigned int* pcnt = cnts + (g * 2 + (s ^ 1)) * 16;
  unsigned* zs32 = (unsigned*)zs;                  // zs as packed u32 words

  int p = 0;
  for (int t = 0; t < Tc; ++t) {
    // early-issue next v; decay acc (independent of partner)
    float vnext = (tid < 256) ? v[vbase + (t + 1 < Tc ? t + 1 : Tc - 1)] : 0.f;
#pragma unroll
    for (int ntl = 0; ntl < 2; ++ntl)
#pragma unroll
      for (int r = 0; r < 4; ++r) acc[ntl][r] *= decay;

    // ---- pre-barrier: spin for partner z(t), load, insert ----
    if (t > 0) {
      int iters = 0;
      while (__hip_atomic_load(pcnt, __ATOMIC_RELAXED,
                               __HIP_MEMORY_SCOPE_AGENT) < (unsigned)(8 * t)) {
        __builtin_amdgcn_s_sleep(2);
        if (++iters > (1 << 22)) break;            // failsafe: no hangs
      }
      asm volatile("" ::: "memory");               // no hoisting past spin
      u32x4 pz4 = *(const u32x4*)(zs32 +
            ((size_t)(t - 1) * Bc + b0 + ptrial) * 256 + (pk >> 1));
      u32x4 av;
#pragma unroll
      for (int j2 = 0; j2 < 4; ++j2) {
        unsigned wd = pz4[j2];
        float lo = __builtin_bit_cast(float, wd << 16);
        float hi = __builtin_bit_cast(float, wd & 0xFFFF0000u);
        lo = lo - hpart[j2 * 2];
        hi = hi - hpart[j2 * 2 + 1];
        lo = lo > 0.f ? lo : 0.f;
        hi = hi > 0.f ? hi : 0.f;
        av[j2] = cvt_pk_bf16(lo, hi);
      }
      *(u32x4*)&abuf[p][ptrial][pk] = av;
    }

    // ---- THE barrier: orders inserts (this step) + own-a/v tail writes
    // (previous step) against the MFMA reads below ----
    asm volatile("s_waitcnt lgkmcnt(0)\n\ts_barrier" ::: "memory");

    // ---- dense MFMA block: all 17 kts ----
#pragma unroll
    for (int kt = 0; kt < 17; ++kt) {
      s16x8 af = *(const s16x8*)&abuf[p][l15][kt * 32 + lg * 8];
      acc[0] = __builtin_amdgcn_mfma_f32_16x16x32_bf16(af, wr[kt * 2 + 0], acc[0], 0, 0, 0);
      acc[1] = __builtin_amdgcn_mfma_f32_16x16x32_bf16(af, wr[kt * 2 + 1], acc[1], 0, 0, 0);
    }

    // ---- tail: z(t+1) -> zs[t] (packed u32 agent stores, issue first) ----
    const size_t zrow0 = (size_t)t * Bc + b0 + lg * 4;
#pragma unroll
    for (int r = 0; r < 4; ++r) {
      float d0 = dpp_swap1(acc[0][r]);
      float d1 = dpp_swap1(acc[1][r]);
      if (!(lane & 1)) {
        unsigned c0 = cvt_pk_bf16(acc[0][r], d0);
        unsigned c1 = cvt_pk_bf16(acc[1][r], d1);
        unsigned* dst = zs32 + (zrow0 + r) * 256 + (nbase >> 1) + (l15 >> 1);
        __hip_atomic_store(dst, c0, __ATOMIC_RELAXED, __HIP_MEMORY_SCOPE_AGENT);
        __hip_atomic_store(dst + 8, c1, __ATOMIC_RELAXED, __HIP_MEMORY_SCOPE_AGENT);
      }
    }

    // ---- tail: own a(t+1) -> abuf[p^1] + v(t+1) rows ----
#pragma unroll
    for (int r = 0; r < 4; ++r) {
      float a0 = acc[0][r] - hreg[0]; a0 = a0 > 0.f ? a0 : 0.f;
      float a1 = acc[1][r] - hreg[1]; a1 = a1 > 0.f ? a1 : 0.f;
      float d0 = dpp_swap1(a0);
      float d1 = dpp_swap1(a1);
      if (!(lane & 1)) {
        unsigned c0 = cvt_pk_bf16(a0, d0);
        unsigned c1 = cvt_pk_bf16(a1, d1);
        *(unsigned*)&abuf[p ^ 1][lg * 4 + r][nbase + (l15 & ~1)] = c0;
        *(unsigned*)&abuf[p ^ 1][lg * 4 + r][nbase + 16 + (l15 & ~1)] = c1;
      }
    }
    if (tid < 256) {
      unsigned short hi = f2bf(vnext);
      abuf[p ^ 1][trr][512 + du] = hi;
      abuf[p ^ 1][trr][528 + du] = f2bf(vnext - bf2f(hi));
    }

    // ---- per-wave drain + publish; NO end-of-step barrier ----
    asm volatile("s_waitcnt vmcnt(0)" ::: "memory");
    if (lane == 0)
      __hip_atomic_fetch_add((unsigned*)mycnt, 1u, __ATOMIC_RELAXED,
                             __HIP_MEMORY_SCOPE_AGENT);
    p ^= 1;
    vcur = vnext;
  }
}

// Projection: x[b][xo][t] = sum_z B_obs[z][xo] * zs[t][b][z] + Bias[xo].
// One WG (256 thr = 4 waves) per (b, 16-t tile); 63 tiles (last masked).
__global__ __launch_bounds__(256, 1) void rnn_proj_kernel(
    const unsigned short* __restrict__ zs, const unsigned short* __restrict__ Bp,
    const float* __restrict__ Bias, float* __restrict__ x) {
  const int wg = blockIdx.x;                       // 64*63 = 4032
  const int b = wg / 63;
  const int tbase = (wg % 63) * 16;
  const int tid = threadIdx.x;
  const int lane = tid & 63;
  const int w = tid >> 6;
  const int l15 = lane & 15, lg = lane >> 4;

  const int trow = tbase + l15;
  const int trc = trow < Tc ? trow : Tc - 1;
  const unsigned short* abase = zs + ((size_t)trc * Bc + b) * DZc + lg * 8;
  const s16x8 zz = {0, 0, 0, 0, 0, 0, 0, 0};

  f32x4 acc[4];
#pragma unroll
  for (int n = 0; n < 4; ++n)
#pragma unroll
    for (int e = 0; e < 4; ++e) acc[n][e] = 0.f;

#pragma unroll
  for (int kt = 0; kt < 16; ++kt) {
    s16x8 af = *(const s16x8*)(abase + kt * 32);
    af = (trow < Tc) ? af : zz;                    // mask pad t-rows
#pragma unroll
    for (int n = 0; n < 4; ++n) {
      s16x8 bf = *(const s16x8*)(Bp + (size_t)((kt * 16 + w * 4 + n) * 64 + lane) * 8);
      acc[n] = __builtin_amdgcn_mfma_f32_16x16x32_bf16(af, bf, acc[n], 0, 0, 0);
    }
  }

  const int t = tbase + lg * 4;                    // regs cover t..t+3
  if (t < Tc) {
#pragma unroll
    for (int n = 0; n < 4; ++n) {
      int xo = (w * 4 + n) * 16 + l15;
      float bias = Bias[xo];
      f32x4 val = acc[n];
#pragma unroll
      for (int e = 0; e < 4; ++e) val[e] += bias;
      *(f32x4*)(x + ((size_t)b * DXc + xo) * Tc + t) = val;
    }
  }
}

extern "C" void kernel_launch(void* const* d_in, const int* in_sizes, int n_in,
                              void* d_out, int out_size, void* d_ws, size_t ws_size,
                              hipStream_t stream) {
  const float* z0   = (const float*)d_in[0];
  const float* v    = (const float*)d_in[1];
  const float* W    = (const float*)d_in[2];
  const float* Wu   = (const float*)d_in[3];
  const float* h    = (const float*)d_in[4];
  const float* dp   = (const float*)d_in[5];
  const float* Bo   = (const float*)d_in[6];
  const float* Bias = (const float*)d_in[7];
  float* x = (float*)d_out;

  unsigned short* Wp = (unsigned short*)d_ws;          // 278528 ushort
  unsigned short* Bp = Wp + 278528;                    // 131072 ushort
  unsigned short* zs = Bp + 131072;                    // 1000*64*512 ushort
  unsigned int* cnts = (unsigned int*)(zs + 32768000); // 128 u32

  hipMemsetAsync(cnts, 0, 128 * sizeof(unsigned int), stream);
  pack_w_kernel<<<1088, 256, 0, stream>>>(W, Wu, Wp);
  pack_b_kernel<<<512, 256, 0, stream>>>(Bo, Bp);
  rnn_rec_kernel<<<16, 512, 0, stream>>>(z0, v, h, dp, Wp, zs, cnts);
  rnn_proj_kernel<<<4032, 256, 0, stream>>>(zs, Bp, Bias, x);
}

// Round 12
// 1953.845 us; speedup vs baseline: 1.1941x; 1.1941x over previous
//
#include <hip/hip_runtime.h>

// Sizes (fixed by the problem)
#define DZc 512
#define Bc  64
#define Tc  1000
#define DUc 16
#define DXc 256
#define AROW 552           // padded activation row length (bf16 elems)

// Workspace layout:
//   Wp   : bf16 augmented W' [544 k][512 n] B-fragment order  278528 ushort
//   Bp   : bf16 B_obs in B-fragment order                     131072 ushort
//   zs   : bf16 z-history [T][B][DZ]                          32768000 ushort
//   cnts : per-(group,half) {flag, xcc} slots, 64-B strided   128 u32

typedef __attribute__((ext_vector_type(4))) float f32x4;
typedef __attribute__((ext_vector_type(8))) short s16x8;
typedef __attribute__((ext_vector_type(4))) unsigned u32x4;

__device__ __forceinline__ unsigned short f2bf(float x) {
  unsigned u = __builtin_bit_cast(unsigned, x);
  u = u + 0x7FFFu + ((u >> 16) & 1u);   // round-to-nearest-even
  return (unsigned short)(u >> 16);
}
__device__ __forceinline__ float bf2f(unsigned short u) {
  unsigned x = ((unsigned)u) << 16;
  return __builtin_bit_cast(float, x);
}
// HW packed f32x2 -> bf16x2 convert (no builtin on gfx950; RNE)
__device__ __forceinline__ unsigned cvt_pk_bf16(float lo, float hi) {
  unsigned r;
  asm("v_cvt_pk_bf16_f32 %0, %1, %2" : "=v"(r) : "v"(lo), "v"(hi));
  return r;
}
// even<->odd lane f32 swap (quad_perm [1,0,3,2])
__device__ __forceinline__ float dpp_swap1(float x) {
  int r = __builtin_amdgcn_mov_dpp(__builtin_bit_cast(int, x), 0xB1, 0xF, 0xF, true);
  return __builtin_bit_cast(float, r);
}

// Pack augmented W' into bf16 MFMA B-fragments.
// W'[n][k]: k<512 -> W[n][k]; k in [512,544) -> Wu[n][k&15].
// Fragment (kt,nt): lane l elem j holds B[k][n], n = nt*16+(l&15),
// k = kt*32+(l>>4)*8+j.  Linear: Wp[((kt*32+nt)*64+l)*8+j]
__global__ void pack_w_kernel(const float* __restrict__ W,
                              const float* __restrict__ Wu,
                              unsigned short* __restrict__ Wp) {
  int d = blockIdx.x * 256 + threadIdx.x;          // 278528 total
  int j = d & 7, l = (d >> 3) & 63, nt = (d >> 9) & 31, kt = d >> 14;
  int n = nt * 16 + (l & 15);
  int k = kt * 32 + ((l >> 4) << 3) + j;
  float val = (k < DZc) ? W[n * DZc + k] : Wu[n * DUc + (k & 15)];
  Wp[d] = f2bf(val);
}

// Pack B_obs[512][256] ([z][x]) into bf16 B-fragments: B[k][n] = B_obs[k][n].
__global__ void pack_b_kernel(const float* __restrict__ B,
                              unsigned short* __restrict__ Bp) {
  int d = blockIdx.x * 256 + threadIdx.x;          // 131072 total
  int j = d & 7, l = (d >> 3) & 63, nt = (d >> 9) & 15, kt = d >> 13;
  int n = nt * 16 + (l & 15);
  int k = kt * 32 + ((l >> 4) << 3) + j;
  Bp[d] = f2bf(B[k * DXc + n]);
}

// Recurrence, N-split pairs: 8 active WGs = 4 trial-groups x 2 n-halves.
// 8 waves x 64 (2/SIMD), 16 trials, 256 outputs/CU; 34 W-frags/wave in regs.
// Exchange: pair detects same-XCD placement at runtime (HW_REG_XCC_ID);
// if same, z-halves move through the SHARED XCD L2 via plain stores/loads
// (coherence point for both CUs); else agent-scope atomic stores (r6 path).
// 2 barriers/step; flag published before the a-write tail (early publish).
__global__ __launch_bounds__(512, 2) void rnn_rec_kernel(
    const float* __restrict__ z0, const float* __restrict__ v,
    const float* __restrict__ h, const float* __restrict__ dp,
    const unsigned short* __restrict__ Wp, unsigned short* __restrict__ zs,
    unsigned int* __restrict__ cnts) {
  __shared__ __align__(16) unsigned short abuf[2][16][AROW];   // 34.5 KiB
  __shared__ unsigned mode_sh;

  const int bid = blockIdx.x;
  const int g = bid & 7;                           // trial group candidate
  const int s = bid >> 3;                          // n-half
  if (g >= 4) return;                              // 8 idle blocks exit
  const int tid = threadIdx.x;
  const int lane = tid & 63;
  const int w = tid >> 6;                          // wave 0..7
  const int l15 = lane & 15;
  const int lg = lane >> 4;
  const int b0 = g * 16;
  const int nbase = s * 256 + w * 32;              // wave's first output

  // publish slots, 64-B strided: [0] = step flag, [1] = xcc id | 0x10
  unsigned int* mycnt = cnts + (g * 2 + s) * 16;
  const unsigned int* pcnt = cnts + (g * 2 + (s ^ 1)) * 16;

  // ---- runtime same-XCD detection (correctness-safe placement probe) ----
  if (tid == 0) {
    unsigned x;
    asm volatile("s_getreg_b32 %0, hwreg(HW_REG_XCC_ID)" : "=s"(x));
    x &= 0xFu;
    __hip_atomic_store(mycnt + 1, x | 0x10u, __ATOMIC_RELAXED,
                       __HIP_MEMORY_SCOPE_AGENT);
    unsigned px; int it = 0;
    do {
      px = __hip_atomic_load(pcnt + 1, __ATOMIC_RELAXED,
                             __HIP_MEMORY_SCOPE_AGENT);
    } while (!(px & 0x10u) && ++it < (1 << 20));
    mode_sh = ((px & 0x10u) && ((px & 0xFu) == x)) ? 1u : 0u;
  }

  // ---- one-time: 34 W fragments into regs, straight kt ordering ----
  s16x8 wr[34];
#pragma unroll
  for (int kt = 0; kt < 17; ++kt) {
#pragma unroll
    for (int ntl = 0; ntl < 2; ++ntl) {
      int nt = s * 16 + w * 2 + ntl;
      wr[kt * 2 + ntl] =
          *(const s16x8*)(Wp + ((size_t)((kt * 32 + nt) * 64 + lane)) * 8);
    }
  }

  // ---- one-time: z0 into acc, h into regs ----
  float hreg[2];
  f32x4 acc[2];
#pragma unroll
  for (int ntl = 0; ntl < 2; ++ntl) {
    hreg[ntl] = h[nbase + ntl * 16 + l15];
#pragma unroll
    for (int r = 0; r < 4; ++r)
      acc[ntl][r] = z0[(size_t)(b0 + lg * 4 + r) * DZc + nbase + ntl * 16 + l15];
  }
  const float decay = expf(-expf(dp[0]));

  // partner-insert slot: thread -> (trial, 8-k chunk of partner half)
  const int ptrial = tid >> 5;                     // 0..15
  const int koff = (tid & 31) * 8;                 // 0..248
  const int pk = (1 - s) * 256 + koff;             // partner k base
  float hpart[8];
#pragma unroll
  for (int j = 0; j < 8; ++j) hpart[j] = h[pk + j];

  // v staging: threads 0..255 own one (trial, du) slot
  const int du = tid & 15, trr = tid >> 4;
  const size_t vbase = ((size_t)(b0 + trr) * DUc + du) * Tc;
  float vcur = (tid < 256) ? v[vbase] : 0.f;

  // ---- prologue: build FULL a(0) from z0 (f32) + v(0) ----
#pragma unroll
  for (int half = 0; half < 2; ++half) {
    int kk = half * 256 + koff;
    const float* zp = z0 + (size_t)(b0 + ptrial) * DZc + kk;
    s16x8 ov;
#pragma unroll
    for (int j = 0; j < 8; ++j) {
      float av = zp[j] - h[kk + j];
      ov[j] = (short)f2bf(av > 0.f ? av : 0.f);
    }
    *(s16x8*)&abuf[0][ptrial][kk] = ov;
  }
  if (tid < 256) {
    unsigned short hi = f2bf(vcur);
    abuf[0][trr][512 + du] = hi;
    abuf[0][trr][528 + du] = f2bf(vcur - bf2f(hi));
  }
  asm volatile("s_waitcnt lgkmcnt(0)\n\ts_barrier" ::: "memory");
  const bool fast = (mode_sh != 0);                // block-uniform

  unsigned* zs32 = (unsigned*)zs;                  // zs as packed u32 words

  int p = 0;
  for (int t = 0; t < Tc; ++t) {
    // early-issue next v; decay acc (independent of partner)
    float vnext = (tid < 256) ? v[vbase + (t + 1 < Tc ? t + 1 : Tc - 1)] : 0.f;
#pragma unroll
    for (int ntl = 0; ntl < 2; ++ntl)
#pragma unroll
      for (int r = 0; r < 4; ++r) acc[ntl][r] *= decay;

    // ---- phase 1: spin for partner z(t), load, insert into abuf[p] ----
    if (t > 0) {
      int iters = 0;
      while (__hip_atomic_load(pcnt, __ATOMIC_RELAXED,
                               __HIP_MEMORY_SCOPE_AGENT) < (unsigned)t) {
        __builtin_amdgcn_s_sleep(2);
        if (++iters > (1 << 22)) break;            // failsafe: no hangs
      }
      asm volatile("" ::: "memory");               // no hoisting past spin
      u32x4 pz4 = *(const u32x4*)(zs32 +
            ((size_t)(t - 1) * Bc + b0 + ptrial) * 256 + (pk >> 1));
      u32x4 av;
#pragma unroll
      for (int j2 = 0; j2 < 4; ++j2) {
        unsigned wd = pz4[j2];
        float lo = __builtin_bit_cast(float, wd << 16);
        float hi = __builtin_bit_cast(float, wd & 0xFFFF0000u);
        lo = lo - hpart[j2 * 2];
        hi = hi - hpart[j2 * 2 + 1];
        lo = lo > 0.f ? lo : 0.f;
        hi = hi > 0.f ? hi : 0.f;
        av[j2] = cvt_pk_bf16(lo, hi);
      }
      *(u32x4*)&abuf[p][ptrial][pk] = av;
    }

    // ---- barrier alpha: inserts (this step) + a/v tail writes (previous
    // step) visible to all waves before the MFMA reads ----
    asm volatile("s_waitcnt lgkmcnt(0)\n\ts_barrier" ::: "memory");

    // ---- dense MFMA block: all 17 kts ----
#pragma unroll
    for (int kt = 0; kt < 17; ++kt) {
      s16x8 af = *(const s16x8*)&abuf[p][l15][kt * 32 + lg * 8];
      acc[0] = __builtin_amdgcn_mfma_f32_16x16x32_bf16(af, wr[kt * 2 + 0], acc[0], 0, 0, 0);
      acc[1] = __builtin_amdgcn_mfma_f32_16x16x32_bf16(af, wr[kt * 2 + 1], acc[1], 0, 0, 0);
    }

    // ---- z(t+1) -> zs[t]: plain stores (same-XCD L2) or agent atomics ----
    const size_t zrow0 = (size_t)t * Bc + b0 + lg * 4;
#pragma unroll
    for (int r = 0; r < 4; ++r) {
      float d0 = dpp_swap1(acc[0][r]);
      float d1 = dpp_swap1(acc[1][r]);
      if (!(lane & 1)) {
        unsigned c0 = cvt_pk_bf16(acc[0][r], d0);
        unsigned c1 = cvt_pk_bf16(acc[1][r], d1);
        unsigned* dst = zs32 + (zrow0 + r) * 256 + (nbase >> 1) + (l15 >> 1);
        if (fast) {
          dst[0] = c0;
          dst[8] = c1;
        } else {
          __hip_atomic_store(dst, c0, __ATOMIC_RELAXED, __HIP_MEMORY_SCOPE_AGENT);
          __hip_atomic_store(dst + 8, c1, __ATOMIC_RELAXED, __HIP_MEMORY_SCOPE_AGENT);
        }
      }
    }

    // ---- barrier beta: all waves' z stores drained; publish EARLY ----
    asm volatile("s_waitcnt vmcnt(0)" ::: "memory");
    __builtin_amdgcn_s_barrier();
    if (tid == 0)
      __hip_atomic_store(mycnt, (unsigned)(t + 1), __ATOMIC_RELAXED,
                         __HIP_MEMORY_SCOPE_AGENT);

    // ---- tail: own a(t+1) -> abuf[p^1] + v(t+1) rows (ordered by next
    // step's barrier alpha) ----
#pragma unroll
    for (int r = 0; r < 4; ++r) {
      float a0 = acc[0][r] - hreg[0]; a0 = a0 > 0.f ? a0 : 0.f;
      float a1 = acc[1][r] - hreg[1]; a1 = a1 > 0.f ? a1 : 0.f;
      float d0 = dpp_swap1(a0);
      float d1 = dpp_swap1(a1);
      if (!(lane & 1)) {
        unsigned c0 = cvt_pk_bf16(a0, d0);
        unsigned c1 = cvt_pk_bf16(a1, d1);
        *(unsigned*)&abuf[p ^ 1][lg * 4 + r][nbase + (l15 & ~1)] = c0;
        *(unsigned*)&abuf[p ^ 1][lg * 4 + r][nbase + 16 + (l15 & ~1)] = c1;
      }
    }
    if (tid < 256) {
      unsigned short hi = f2bf(vnext);
      abuf[p ^ 1][trr][512 + du] = hi;
      abuf[p ^ 1][trr][528 + du] = f2bf(vnext - bf2f(hi));
    }

    p ^= 1;
    vcur = vnext;
  }
}

// Projection: x[b][xo][t] = sum_z B_obs[z][xo] * zs[t][b][z] + Bias[xo].
// One WG (256 thr = 4 waves) per (b, 16-t tile); 63 tiles (last masked).
__global__ __launch_bounds__(256, 1) void rnn_proj_kernel(
    const unsigned short* __restrict__ zs, const unsigned short* __restrict__ Bp,
    const float* __restrict__ Bias, float* __restrict__ x) {
  const int wg = blockIdx.x;                       // 64*63 = 4032
  const int b = wg / 63;
  const int tbase = (wg % 63) * 16;
  const int tid = threadIdx.x;
  const int lane = tid & 63;
  const int w = tid >> 6;
  const int l15 = lane & 15, lg = lane >> 4;

  const int trow = tbase + l15;
  const int trc = trow < Tc ? trow : Tc - 1;
  const unsigned short* abase = zs + ((size_t)trc * Bc + b) * DZc + lg * 8;
  const s16x8 zz = {0, 0, 0, 0, 0, 0, 0, 0};

  f32x4 acc[4];
#pragma unroll
  for (int n = 0; n < 4; ++n)
#pragma unroll
    for (int e = 0; e < 4; ++e) acc[n][e] = 0.f;

#pragma unroll
  for (int kt = 0; kt < 16; ++kt) {
    s16x8 af = *(const s16x8*)(abase + kt * 32);
    af = (trow < Tc) ? af : zz;                    // mask pad t-rows
#pragma unroll
    for (int n = 0; n < 4; ++n) {
      s16x8 bf = *(const s16x8*)(Bp + (size_t)((kt * 16 + w * 4 + n) * 64 + lane) * 8);
      acc[n] = __builtin_amdgcn_mfma_f32_16x16x32_bf16(af, bf, acc[n], 0, 0, 0);
    }
  }

  const int t = tbase + lg * 4;                    // regs cover t..t+3
  if (t < Tc) {
#pragma unroll
    for (int n = 0; n < 4; ++n) {
      int xo = (w * 4 + n) * 16 + l15;
      float bias = Bias[xo];
      f32x4 val = acc[n];
#pragma unroll
      for (int e = 0; e < 4; ++e) val[e] += bias;
      *(f32x4*)(x + ((size_t)b * DXc + xo) * Tc + t) = val;
    }
  }
}

extern "C" void kernel_launch(void* const* d_in, const int* in_sizes, int n_in,
                              void* d_out, int out_size, void* d_ws, size_t ws_size,
                              hipStream_t stream) {
  const float* z0   = (const float*)d_in[0];
  const float* v    = (const float*)d_in[1];
  const float* W    = (const float*)d_in[2];
  const float* Wu   = (const float*)d_in[3];
  const float* h    = (const float*)d_in[4];
  const float* dp   = (const float*)d_in[5];
  const float* Bo   = (const float*)d_in[6];
  const float* Bias = (const float*)d_in[7];
  float* x = (float*)d_out;

  unsigned short* Wp = (unsigned short*)d_ws;          // 278528 ushort
  unsigned short* Bp = Wp + 278528;                    // 131072 ushort
  unsigned short* zs = Bp + 131072;                    // 1000*64*512 ushort
  unsigned int* cnts = (unsigned int*)(zs + 32768000); // 128 u32

  hipMemsetAsync(cnts, 0, 128 * sizeof(unsigned int), stream);
  pack_w_kernel<<<1088, 256, 0, stream>>>(W, Wu, Wp);
  pack_b_kernel<<<512, 256, 0, stream>>>(Bo, Bp);
  rnn_rec_kernel<<<16, 512, 0, stream>>>(z0, v, h, dp, Wp, zs, cnts);
  rnn_proj_kernel<<<4032, 256, 0, stream>>>(zs, Bp, Bias, x);
}